// Round 6
// baseline (233.422 us; speedup 1.0000x reference)
//
#include <hip/hip_runtime.h>
#include <math.h>

#define B     4096
#define ND    13
#define NS    26
#define NF    39
#define VOCAB 100000
#define NP    351      // l<=m pairs in 26x26
#define NPP   360      // padded to 8 chunks * 45
#define CHP   45       // p's per wave-chunk
#define GSTR  28       // Gst row: [0..25]=Gs_j, [26]=A1s, [27]=lut bits
#define RPB   8        // rows per block
#define NT    512      // threads per block (8 waves)
#define XSS   212

// ---------------- workspace layout (floats) ----------------
#define OFF_GST 0        // 360*28 = 10080
#define OFF_CST 10080    // 1
#define OFF_C2J 10088    // 26

// ---- single merged precompute kernel, 28 independent blocks ----
__global__ __launch_bounds__(256) void k_pre(const float* __restrict__ W0,
                                             const float* __restrict__ W1,
                                             const float* __restrict__ b0,
                                             const float* __restrict__ b1,
                                             const float* __restrict__ clw,
                                             float* __restrict__ Gst,
                                             float* __restrict__ cst,
                                             float* __restrict__ c2j) {
    int blk = blockIdx.x, tid = threadIdx.x;
    if (blk < 26) {
        int j = blk;
        __shared__ float vh[2][128];
        __shared__ float vj[128];
        __shared__ float c2r[2];
        {
            int i = tid & 127, h = tid >> 7;
            const float* wp = W1 + (long)(h * 64) * 3328 + i * 26 + j;
            float acc = 0.f;
#pragma unroll 8
            for (int o = 0; o < 64; o++) acc += clw[128 + h * 64 + o] * wp[o * 3328];
            vh[h][i] = acc;
        }
        __syncthreads();
        if (tid < 128) {
            float vv = vh[0][tid] + vh[1][tid];
            vj[tid] = vv;
            float c = vv * b0[tid];
            for (int off = 32; off; off >>= 1) c += __shfl_down(c, off, 64);
            if ((tid & 63) == 0) c2r[tid >> 6] = c;
        }
        __syncthreads();
        if (tid == 0) c2j[j] = c2r[0] + c2r[1];
        for (int p = tid; p < NPP; p += 256) {
            float g = 0.f;
            if (p < NP) {
                int l = 0, rem = p;
                while (rem >= NS - l) { rem -= NS - l; l++; }
                int m = l + rem;
                float sym = (l != m) ? 1.f : 0.f;
                const float* wa = W0 + l * 26 + m;
                const float* wb = W0 + m * 26 + l;
#pragma unroll 8
                for (int i = 0; i < 128; i++)
                    g += vj[i] * (wa[i * 676] + sym * wb[i * 676]);
            }
            Gst[p * GSTR + j] = g;
        }
    } else if (blk == 26) {
        for (int p = tid; p < NPP; p += 256) {
            float a = 0.f; int lmbits = 0;
            if (p < NP) {
                int l = 0, rem = p;
                while (rem >= NS - l) { rem -= NS - l; l++; }
                int m = l + rem;
                float sym = (l != m) ? 1.f : 0.f;
                const float* wa = W0 + l * 26 + m;
                const float* wb = W0 + m * 26 + l;
#pragma unroll 8
                for (int o = 0; o < 128; o++)
                    a += clw[o] * (wa[o * 676] + sym * wb[o * 676]);
                lmbits = (l << 5) | m;
            }
            Gst[p * GSTR + 26] = a;
            Gst[p * GSTR + 27] = __int_as_float(lmbits);
        }
    } else {
        __shared__ float red[2];
        float c = 0.f;
        if (tid < 128) {
            c = clw[tid] * b0[tid] + clw[128 + tid] * b1[tid];
            for (int off = 32; off; off >>= 1) c += __shfl_down(c, off, 64);
            if ((tid & 63) == 0) red[tid >> 6] = c;
        }
        __syncthreads();
        if (tid == 0) cst[0] = 8.f * (red[0] + red[1]);
    }
}

// ---- fused main: gather + linear + CIN (wave-uniform scalar Gst) + DNN ----
// 8 rows/block, 512 threads (8 waves), one 45-p chunk per wave.
__global__ __launch_bounds__(NT, 4) void k_main(
    const float* __restrict__ inputs, const float* __restrict__ tables,
    const float* __restrict__ lW, const float* __restrict__ lb,
    const float* __restrict__ Gst, const float* __restrict__ c2j,
    const float* __restrict__ cst,
    const float* __restrict__ dW1, const float* __restrict__ db1,
    const float* __restrict__ dW2, const float* __restrict__ db2,
    const float* __restrict__ dW3, const float* __restrict__ db3,
    const float* __restrict__ dW4, const float* __restrict__ db4,
    const float* __restrict__ clb,
    float* __restrict__ out) {
    __shared__ float insf[RPB][40];      // 1.28 KB
    __shared__ float xs[RPB][XSS];       // 6.8 KB  emb per row, CIN layout
    __shared__ float inT[256][RPB];      // 8 KB    DNN input transposed
    __shared__ float h1T[256][RPB];      // 8 KB
    __shared__ float h2T[128][RPB];      // 4 KB
    __shared__ float pbuf[NT][RPB];      // 16 KB   split-K partials
    __shared__ float lin_s[RPB], scin_s[RPB];
    __shared__ float redbuf[8][RPB];

    int tid = threadIdx.x;
    int b0r = blockIdx.x * RPB;

    // phase 1: raw inputs
    if (tid < RPB * NF) {
        int r = tid / NF, c = tid - r * NF;
        insf[r][c] = inputs[(b0r + r) * NF + c];
    }
    __syncthreads();

    // phase 2: gather embeddings (both layouts) + dense cols + linear term
    if (tid < RPB * NS) {
        int r = tid / NS, f = tid - r * NS;
        int idx = (int)insf[r][ND + f];
        const float4* src = (const float4*)(tables + ((long)f * VOCAB + idx) * 8);
        float4 a = src[0], b4 = src[1];
        float4* dst = (float4*)&xs[r][f * 8];
        dst[0] = a; dst[1] = b4;
        int cb = ND + f * 8;
        inT[cb + 0][r] = a.x;  inT[cb + 1][r] = a.y;
        inT[cb + 2][r] = a.z;  inT[cb + 3][r] = a.w;
        inT[cb + 4][r] = b4.x; inT[cb + 5][r] = b4.y;
        inT[cb + 6][r] = b4.z; inT[cb + 7][r] = b4.w;
    } else if (tid >= 256 && tid < 256 + RPB * ND) {
        int t = tid - 256;
        int r = t / ND, c = t - r * ND;
        inT[c][r] = insf[r][c];
    } else if (tid >= 384 && tid < 384 + RPB) {
        int r = tid - 384;
        float acc = lb[0];
        for (int c = 0; c < NF; c++) acc += insf[r][c] * lW[c];
        lin_s[r] = acc;
    }
    __syncthreads();

    // phase 3: CIN. wave w owns chunk w (45 p's); lane = (r, k). Gst rows are
    // wave-uniform -> scalar loads; x reads are per-lane LDS broadcasts.
    {
        int lane = tid & 63;
        int w = tid >> 6;
        int chunk = __builtin_amdgcn_readfirstlane(w);   // force SGPR-uniform
        int r = lane >> 3, k = lane & 7;
        const float* xrow = &xs[r][0];
        const float* gr = Gst + chunk * (CHP * GSTR);
        float t[27];
#pragma unroll
        for (int j = 0; j < 27; j++) t[j] = 0.f;
        for (int pi = 0; pi < CHP; pi++) {
            const float* g = gr + pi * GSTR;             // uniform row base
            int lm = __float_as_int(g[27]);              // scalar
            float q = xrow[(lm >> 5) * 8 + k] * xrow[(lm & 31) * 8 + k];
#pragma unroll
            for (int j = 0; j < 27; j++) t[j] += g[j] * q;
        }
        float csel = (chunk == 0) ? 1.f : 0.f;
        float part = t[26];                              // A1 (quadratic) term
#pragma unroll
        for (int j = 0; j < 26; j++)
            part += (t[j] + csel * c2j[j]) * xrow[j * 8 + k];
        part += __shfl_xor(part, 1, 64);
        part += __shfl_xor(part, 2, 64);
        part += __shfl_xor(part, 4, 64);
        if (k == 0) redbuf[w][r] = part;
    }
    __syncthreads();

    // phase 4: scin finalize + DNN layer1 (221 -> 256), split-K x2
    if (tid < RPB) {
        float s = cst[0];
#pragma unroll
        for (int w = 0; w < 8; w++) s += redbuf[w][tid];
        scin_s[tid] = s;
    }
    {
        int o = tid & 255, cg = tid >> 8;
        int c0 = cg ? 111 : 0, c1 = cg ? 221 : 111;
        float bias = cg ? 0.f : db1[o];
        float a0 = bias, a1 = bias, a2 = bias, a3 = bias;
        float a4 = bias, a5 = bias, a6 = bias, a7 = bias;
        for (int c = c0; c < c1; c++) {
            float wv = dW1[c * 256 + o];
            float4 i0 = *(const float4*)&inT[c][0];
            float4 i1 = *(const float4*)&inT[c][4];
            a0 += i0.x * wv; a1 += i0.y * wv; a2 += i0.z * wv; a3 += i0.w * wv;
            a4 += i1.x * wv; a5 += i1.y * wv; a6 += i1.z * wv; a7 += i1.w * wv;
        }
        *(float4*)&pbuf[tid][0] = make_float4(a0, a1, a2, a3);
        *(float4*)&pbuf[tid][4] = make_float4(a4, a5, a6, a7);
    }
    __syncthreads();
    if (tid < 256) {
        float4 p0 = *(const float4*)&pbuf[tid][0];
        float4 p1 = *(const float4*)&pbuf[tid][4];
        float4 q0 = *(const float4*)&pbuf[tid + 256][0];
        float4 q1 = *(const float4*)&pbuf[tid + 256][4];
        float4 o0, o1;
        o0.x = fmaxf(p0.x + q0.x, 0.f); o0.y = fmaxf(p0.y + q0.y, 0.f);
        o0.z = fmaxf(p0.z + q0.z, 0.f); o0.w = fmaxf(p0.w + q0.w, 0.f);
        o1.x = fmaxf(p1.x + q1.x, 0.f); o1.y = fmaxf(p1.y + q1.y, 0.f);
        o1.z = fmaxf(p1.z + q1.z, 0.f); o1.w = fmaxf(p1.w + q1.w, 0.f);
        *(float4*)&h1T[tid][0] = o0;
        *(float4*)&h1T[tid][4] = o1;
    }
    __syncthreads();

    // phase 5: layer2 (256 -> 128), split-K x4
    {
        int o = tid & 127, cg = tid >> 7;
        float bias = (cg == 0) ? db2[o] : 0.f;
        float a0 = bias, a1 = bias, a2 = bias, a3 = bias;
        float a4 = bias, a5 = bias, a6 = bias, a7 = bias;
        const float* wb = dW2 + o;
        for (int cc = 0; cc < 64; cc++) {
            int c = cg * 64 + cc;
            float wv = wb[c * 128];
            float4 i0 = *(const float4*)&h1T[c][0];
            float4 i1 = *(const float4*)&h1T[c][4];
            a0 += i0.x * wv; a1 += i0.y * wv; a2 += i0.z * wv; a3 += i0.w * wv;
            a4 += i1.x * wv; a5 += i1.y * wv; a6 += i1.z * wv; a7 += i1.w * wv;
        }
        *(float4*)&pbuf[tid][0] = make_float4(a0, a1, a2, a3);
        *(float4*)&pbuf[tid][4] = make_float4(a4, a5, a6, a7);
    }
    __syncthreads();
    if (tid < 128) {
        float s[8];
#pragma unroll
        for (int i = 0; i < 8; i++) s[i] = 0.f;
#pragma unroll
        for (int g = 0; g < 4; g++) {
            float4 p0 = *(const float4*)&pbuf[tid + g * 128][0];
            float4 p1 = *(const float4*)&pbuf[tid + g * 128][4];
            s[0] += p0.x; s[1] += p0.y; s[2] += p0.z; s[3] += p0.w;
            s[4] += p1.x; s[5] += p1.y; s[6] += p1.z; s[7] += p1.w;
        }
        float4 o0, o1;
        o0.x = fmaxf(s[0], 0.f); o0.y = fmaxf(s[1], 0.f);
        o0.z = fmaxf(s[2], 0.f); o0.w = fmaxf(s[3], 0.f);
        o1.x = fmaxf(s[4], 0.f); o1.y = fmaxf(s[5], 0.f);
        o1.z = fmaxf(s[6], 0.f); o1.w = fmaxf(s[7], 0.f);
        *(float4*)&h2T[tid][0] = o0;
        *(float4*)&h2T[tid][4] = o1;
    }
    __syncthreads();

    // phase 6: layer3 (128 -> 64), split-K x8
    {
        int o = tid & 63, cg = tid >> 6;
        float bias = (cg == 0) ? db3[o] : 0.f;
        float a0 = bias, a1 = bias, a2 = bias, a3 = bias;
        float a4 = bias, a5 = bias, a6 = bias, a7 = bias;
        const float* wb = dW3 + o;
        for (int cc = 0; cc < 16; cc++) {
            int c = cg * 16 + cc;
            float wv = wb[c * 64];
            float4 i0 = *(const float4*)&h2T[c][0];
            float4 i1 = *(const float4*)&h2T[c][4];
            a0 += i0.x * wv; a1 += i0.y * wv; a2 += i0.z * wv; a3 += i0.w * wv;
            a4 += i1.x * wv; a5 += i1.y * wv; a6 += i1.z * wv; a7 += i1.w * wv;
        }
        *(float4*)&pbuf[tid][0] = make_float4(a0, a1, a2, a3);
        *(float4*)&pbuf[tid][4] = make_float4(a4, a5, a6, a7);
    }
    __syncthreads();

    // phase 7: combine L3 + layer4 (64 -> 1) + final combine + sigmoid (wave 0)
    if (tid < 64) {
        float s[8];
#pragma unroll
        for (int i = 0; i < 8; i++) s[i] = 0.f;
#pragma unroll
        for (int g = 0; g < 8; g++) {
            float4 p0 = *(const float4*)&pbuf[tid + g * 64][0];
            float4 p1 = *(const float4*)&pbuf[tid + g * 64][4];
            s[0] += p0.x; s[1] += p0.y; s[2] += p0.z; s[3] += p0.w;
            s[4] += p1.x; s[5] += p1.y; s[6] += p1.z; s[7] += p1.w;
        }
        float w4 = dW4[tid];
#pragma unroll
        for (int i = 0; i < 8; i++) s[i] = fmaxf(s[i], 0.f) * w4;
#pragma unroll
        for (int off = 1; off < 64; off <<= 1)
#pragma unroll
            for (int i = 0; i < 8; i++) s[i] += __shfl_xor(s[i], off, 64);
        if (tid == 0) {
            float bb = db4[0], cb = clb[0];
#pragma unroll
            for (int r = 0; r < RPB; r++) {
                float dense = fmaxf(s[r] + bb, 0.f);
                float cin = fmaxf(scin_s[r] + cb, 0.f);
                float x = lin_s[r] + cin + dense;
                out[b0r + r] = 1.f / (1.f + expf(-x));
            }
        }
    }
}

extern "C" void kernel_launch(void* const* d_in, const int* in_sizes, int n_in,
                              void* d_out, int out_size, void* d_ws, size_t ws_size,
                              hipStream_t stream) {
    const float* inputs = (const float*)d_in[0];
    const float* tables = (const float*)d_in[1];
    const float* lW     = (const float*)d_in[2];
    const float* lb     = (const float*)d_in[3];
    const float* W0     = (const float*)d_in[4];
    const float* b0     = (const float*)d_in[5];
    const float* W1c    = (const float*)d_in[6];
    const float* b1c    = (const float*)d_in[7];
    const float* clw    = (const float*)d_in[8];
    const float* clb    = (const float*)d_in[9];
    const float* dW1    = (const float*)d_in[10];
    const float* db1    = (const float*)d_in[11];
    const float* dW2    = (const float*)d_in[12];
    const float* db2    = (const float*)d_in[13];
    const float* dW3    = (const float*)d_in[14];
    const float* db3    = (const float*)d_in[15];
    const float* dW4    = (const float*)d_in[16];
    const float* db4    = (const float*)d_in[17];

    float* ws   = (float*)d_ws;
    float* Gst  = ws + OFF_GST;
    float* cst  = ws + OFF_CST;
    float* c2j  = ws + OFF_C2J;

    k_pre<<<28, 256, 0, stream>>>(W0, W1c, b0, b1c, clw, Gst, cst, c2j);
    k_main<<<B / RPB, NT, 0, stream>>>(inputs, tables, lW, lb, Gst, c2j, cst,
                                       dW1, db1, dW2, db2, dW3, db3, dW4, db4, clb,
                                       (float*)d_out);
}